// Round 1
// baseline (1170.705 us; speedup 1.0000x reference)
//
#include <hip/hip_runtime.h>
#include <hip/hip_bf16.h>

#define NPOS 4096
#define BB 2

__device__ __forceinline__ float pe_val(int C, int c, int ch, int h, int w) {
    int blk = ch / c;
    int j = ch - blk * c;
    int half = c >> 1;
    int jj = (j < half) ? j : j - half;
    // inv_freq = 10000^(-(2*jj)/c)
    float freq = __expf(-(2.0f * jj / (float)c) * 9.210340371976184f); // ln(10000)
    int pos = (blk < 2) ? h : w;   // torch-broadcast quirk: blocks 0,1 -> y(=h), block 2 -> z(=w)
    float s = (float)pos * freq;
    return (j < half) ? __sinf(s) : __cosf(s);
}

__global__ void pe_add_kernel(const float* __restrict__ in, float* __restrict__ out, int C, int c) {
    int idx = blockIdx.x * 256 + threadIdx.x;
    int total = BB * C * NPOS;
    if (idx >= total) return;
    int n = idx & 4095;
    int ch = (idx >> 12) % C;
    int h = (n >> 4) & 15;
    int w = n & 15;
    out[idx] = in[idx] + pe_val(C, c, ch, h, w);
}

// conv1x1 + BN + ReLU.  in: (B,CI,N)  ->  out: (B,N,CO) row-major over CO
template<int CI, int CO>
__global__ void proj_kernel(const float* __restrict__ in, const float* __restrict__ w,
                            const float* __restrict__ bias, const float* __restrict__ g,
                            const float* __restrict__ be, float* __restrict__ out) {
    __shared__ float wl[CO * CI];
    __shared__ float sb[CO], bb[CO];
    int t = threadIdx.x;
    for (int i = t; i < CO * CI; i += 256) wl[i] = w[i];
    if (t < CO) {
        float s = g[t] * rsqrtf(1.0f + 1e-5f);
        sb[t] = s; bb[t] = bias[t] * s + be[t];
    }
    __syncthreads();
    int gn = blockIdx.x * 256 + t;     // over B*N
    if (gn >= BB * NPOS) return;
    int b = gn >> 12; int n = gn & 4095;
    const float* ip = in + (size_t)b * CI * NPOS + n;
    float acc[CO];
#pragma unroll
    for (int o = 0; o < CO; o++) acc[o] = 0.f;
    for (int ci = 0; ci < CI; ci++) {
        float v = ip[(size_t)ci * NPOS];
#pragma unroll
        for (int o = 0; o < CO; o++) acc[o] += v * wl[o * CI + ci];
    }
    float* op = out + (size_t)gn * CO;
#pragma unroll
    for (int o = 0; o < CO; o++) {
        float z = acc[o] * sb[o] + bb[o];
        op[o] = z > 0.f ? z : 0.f;
    }
}

// out[b,n,e] = sum_d in[b,n,d] * W[d,e]   (in,out: (B,N,48), W: (48,48))
__global__ void rmul48_kernel(const float* __restrict__ in, const float* __restrict__ w,
                              float* __restrict__ out) {
    __shared__ float wl[48 * 48];
    int t = threadIdx.x;
    for (int i = t; i < 48 * 48; i += 256) wl[i] = w[i];
    __syncthreads();
    int gn = blockIdx.x * 256 + t;
    if (gn >= BB * NPOS) return;
    const float* ip = in + (size_t)gn * 48;
    float acc[48];
#pragma unroll
    for (int e = 0; e < 48; e++) acc[e] = 0.f;
    for (int d = 0; d < 48; d++) {
        float v = ip[d];
#pragma unroll
        for (int e = 0; e < 48; e++) acc[e] += v * wl[d * 48 + e];
    }
    float* op = out + (size_t)gn * 48;
#pragma unroll
    for (int e = 0; e < 48; e++) op[e] = acc[e];
}

// Pass 1: per-column (over q) online max/sum partials.  grid: b(2) x qt(16) x kt(16)
__global__ void attn_stats_kernel(const float* __restrict__ Q, const float* __restrict__ K,
                                  float* __restrict__ pm, float* __restrict__ ps) {
    int bid = blockIdx.x;
    int kt = bid & 15; int qt = (bid >> 4) & 15; int b = bid >> 8;
    int t = threadIdx.x;
    int k = kt * 256 + t;
    const float* kp = K + ((size_t)b * NPOS + k) * 48;
    float kr[48];
#pragma unroll
    for (int d4 = 0; d4 < 12; d4++) {
        float4 kx = *reinterpret_cast<const float4*>(kp + d4 * 4);
        kr[d4*4+0] = kx.x; kr[d4*4+1] = kx.y; kr[d4*4+2] = kx.z; kr[d4*4+3] = kx.w;
    }
    __shared__ float qtile[256 * 48];
    const float* qp = Q + ((size_t)b * NPOS + qt * 256) * 48;
    for (int i = t; i < 256 * 48; i += 256) qtile[i] = qp[i];
    __syncthreads();
    const float scale = 0.14433756729740643f; // 1/sqrt(48)
    float m = -1e30f, s = 0.f;
    for (int qi = 0; qi < 256; qi++) {
        float l = 0.f;
#pragma unroll
        for (int d4 = 0; d4 < 12; d4++) {
            float4 qx = *reinterpret_cast<const float4*>(&qtile[qi * 48 + d4 * 4]);
            l += kr[d4*4+0]*qx.x + kr[d4*4+1]*qx.y + kr[d4*4+2]*qx.z + kr[d4*4+3]*qx.w;
        }
        l *= scale;
        float mn = fmaxf(m, l);
        s = s * __expf(m - mn) + __expf(l - mn);
        m = mn;
    }
    pm[((size_t)b * 16 + qt) * NPOS + k] = m;
    ps[((size_t)b * 16 + qt) * NPOS + k] = s;
}

__global__ void stats_reduce_kernel(const float* __restrict__ pm, const float* __restrict__ ps,
                                    float* __restrict__ colm, float* __restrict__ colinv) {
    int idx = blockIdx.x * 256 + threadIdx.x;
    if (idx >= BB * NPOS) return;
    int b = idx >> 12; int k = idx & 4095;
    float m = -1e30f;
    for (int qt = 0; qt < 16; qt++) m = fmaxf(m, pm[((size_t)b * 16 + qt) * NPOS + k]);
    float s = 0.f;
    for (int qt = 0; qt < 16; qt++)
        s += ps[((size_t)b * 16 + qt) * NPOS + k] * __expf(pm[((size_t)b * 16 + qt) * NPOS + k] - m);
    colm[idx] = m;
    colinv[idx] = 1.0f / s;
}

// Pass 2: x partials.  grid: b(2) x qt(16) x kt(8); each block does 512 k for 256 q.
__global__ void attn_pv_kernel(const float* __restrict__ Q, const float* __restrict__ K,
                               const float* __restrict__ V, const float* __restrict__ colm,
                               const float* __restrict__ colinv, float* __restrict__ xpart) {
    int bid = blockIdx.x;
    int kt = bid & 7; int qt = (bid >> 3) & 15; int b = bid >> 7;
    int t = threadIdx.x;
    int q = qt * 256 + t;
    const float* qp = Q + ((size_t)b * NPOS + q) * 48;
    float qr[48];
#pragma unroll
    for (int d4 = 0; d4 < 12; d4++) {
        float4 qx = *reinterpret_cast<const float4*>(qp + d4 * 4);
        qr[d4*4+0] = qx.x; qr[d4*4+1] = qx.y; qr[d4*4+2] = qx.z; qr[d4*4+3] = qx.w;
    }
    float acc[48];
#pragma unroll
    for (int d = 0; d < 48; d++) acc[d] = 0.f;
    __shared__ float kl[64 * 48];
    __shared__ float vl[64 * 48];
    __shared__ float sm[64];
    __shared__ float si[64];
    const float scale = 0.14433756729740643f;
    for (int c0 = 0; c0 < 512; c0 += 64) {
        __syncthreads();
        int kbase = kt * 512 + c0;
        for (int i = t; i < 64 * 48; i += 256) {
            kl[i] = K[((size_t)b * NPOS + kbase) * 48 + i];
            vl[i] = V[((size_t)b * NPOS + kbase) * 48 + i];
        }
        if (t < 64) {
            sm[t] = colm[(size_t)b * NPOS + kbase + t];
            si[t] = colinv[(size_t)b * NPOS + kbase + t];
        }
        __syncthreads();
        for (int kk = 0; kk < 64; kk++) {
            float l = 0.f;
#pragma unroll
            for (int d4 = 0; d4 < 12; d4++) {
                float4 kx = *reinterpret_cast<const float4*>(&kl[kk * 48 + d4 * 4]);
                l += qr[d4*4+0]*kx.x + qr[d4*4+1]*kx.y + qr[d4*4+2]*kx.z + qr[d4*4+3]*kx.w;
            }
            float wgt = __expf(l * scale - sm[kk]) * si[kk];
#pragma unroll
            for (int d4 = 0; d4 < 12; d4++) {
                float4 vx = *reinterpret_cast<const float4*>(&vl[kk * 48 + d4 * 4]);
                acc[d4*4+0] += wgt * vx.x; acc[d4*4+1] += wgt * vx.y;
                acc[d4*4+2] += wgt * vx.z; acc[d4*4+3] += wgt * vx.w;
            }
        }
    }
    float* op = xpart + (((size_t)(b * 8 + kt) * NPOS) + q) * 48;
#pragma unroll
    for (int d = 0; d < 48; d++) op[d] = acc[d];
}

// Reduce x partials + conv1x1(w_o) + BN + ReLU, * S_pe -> out channels [0,48)
__global__ void z_out_kernel(const float* __restrict__ xpart, const float* __restrict__ w_o,
                             const float* __restrict__ b_o, const float* __restrict__ g_o,
                             const float* __restrict__ be_o, const float* __restrict__ S_pe,
                             float* __restrict__ out) {
    __shared__ float wl[48 * 48];
    __shared__ float sb[48], bb[48];
    int t = threadIdx.x;
    for (int i = t; i < 48 * 48; i += 256) wl[i] = w_o[i];
    if (t < 48) { float s = g_o[t] * rsqrtf(1.f + 1e-5f); sb[t] = s; bb[t] = b_o[t] * s + be_o[t]; }
    __syncthreads();
    int gn = blockIdx.x * 256 + t;
    if (gn >= BB * NPOS) return;
    int b = gn >> 12; int n = gn & 4095;
    float x[48];
#pragma unroll
    for (int d = 0; d < 48; d++) x[d] = 0.f;
    for (int kt = 0; kt < 8; kt++) {
        const float* p = xpart + (((size_t)(b * 8 + kt) * NPOS) + n) * 48;
#pragma unroll
        for (int d = 0; d < 48; d++) x[d] += p[d];
    }
    for (int o = 0; o < 48; o++) {
        float acc = 0.f;
#pragma unroll
        for (int d = 0; d < 48; d++) acc += wl[o * 48 + d] * x[d];
        float z = acc * sb[o] + bb[o];
        z = z > 0.f ? z : 0.f;
        out[((size_t)b * 96 + o) * NPOS + n] = z * S_pe[((size_t)b * 48 + o) * NPOS + n];
    }
}

// 3x3x3 SAME conv + b3.  grid: b(2) x co(96) x zslab(4), 256 threads = 16x16 plane.
__global__ void conv3d_kernel(const float* __restrict__ Y_pe, const float* __restrict__ w3,
                              const float* __restrict__ b3, float* __restrict__ Y3) {
    int bid = blockIdx.x;
    int zs = bid & 3; int co = (bid >> 2) % 96; int b = bid / (96 * 4);
    int t = threadIdx.x;
    int h = t >> 4; int w = t & 15;
    __shared__ float wl[96 * 27];
    __shared__ float tile[6 * 18 * 18];
    for (int i = t; i < 96 * 27; i += 256) wl[i] = w3[(size_t)co * 96 * 27 + i];
    float acc[4];
#pragma unroll
    for (int i = 0; i < 4; i++) acc[i] = 0.f;
    int z0 = zs * 4;
    for (int ci = 0; ci < 96; ci++) {
        __syncthreads();
        for (int i = t; i < 6 * 18 * 18; i += 256) {
            int tz = i / 324; int r = i - tz * 324; int th = r / 18; int tw = r - th * 18;
            int gz = z0 + tz - 1, gh = th - 1, gw = tw - 1;
            float v = 0.f;
            if (gz >= 0 && gz < 16 && gh >= 0 && gh < 16 && gw >= 0 && gw < 16)
                v = Y_pe[(((size_t)b * 96 + ci) * 4096) + gz * 256 + gh * 16 + gw];
            tile[i] = v;
        }
        __syncthreads();
        const float* wp = &wl[ci * 27];
#pragma unroll
        for (int kh = 0; kh < 3; kh++)
#pragma unroll
            for (int kw = 0; kw < 3; kw++) {
                float col[6];
#pragma unroll
                for (int tz = 0; tz < 6; tz++) col[tz] = tile[tz * 324 + (h + kh) * 18 + (w + kw)];
#pragma unroll
                for (int kd = 0; kd < 3; kd++) {
                    float wv = wp[kd * 9 + kh * 3 + kw];
#pragma unroll
                    for (int zi = 0; zi < 4; zi++) acc[zi] += wv * col[zi + kd];
                }
            }
    }
    float bv = b3[co];
#pragma unroll
    for (int zi = 0; zi < 4; zi++)
        Y3[(((size_t)b * 96 + co) * 4096) + (z0 + zi) * 256 + h * 16 + w] = acc[zi] + bv;
}

// conv1x1(w_y2) + BN + ReLU on Y3 -> out channels [48,96)
__global__ void y2_out_kernel(const float* __restrict__ Y3, const float* __restrict__ w_y2,
                              const float* __restrict__ b_y2, const float* __restrict__ g_y2,
                              const float* __restrict__ be_y2, float* __restrict__ out) {
    __shared__ float wl[48 * 96];
    __shared__ float sb[48], bb[48];
    int t = threadIdx.x;
    for (int i = t; i < 48 * 96; i += 256) wl[i] = w_y2[i];
    if (t < 48) { float s = g_y2[t] * rsqrtf(1.f + 1e-5f); sb[t] = s; bb[t] = b_y2[t] * s + be_y2[t]; }
    __syncthreads();
    int gn = blockIdx.x * 256 + t;
    if (gn >= BB * NPOS) return;
    int b = gn >> 12; int n = gn & 4095;
    const float* ip = Y3 + (size_t)b * 96 * NPOS + n;
    float acc[48];
#pragma unroll
    for (int o = 0; o < 48; o++) acc[o] = 0.f;
    for (int ci = 0; ci < 96; ci++) {
        float v = ip[(size_t)ci * NPOS];
#pragma unroll
        for (int o = 0; o < 48; o++) acc[o] += v * wl[o * 96 + ci];
    }
    for (int o = 0; o < 48; o++) {
        float z = acc[o] * sb[o] + bb[o];
        out[((size_t)b * 96 + 48 + o) * NPOS + n] = z > 0.f ? z : 0.f;
    }
}

extern "C" void kernel_launch(void* const* d_in, const int* in_sizes, int n_in,
                              void* d_out, int out_size, void* d_ws, size_t ws_size,
                              hipStream_t stream) {
    const float* Y    = (const float*)d_in[0];
    const float* S    = (const float*)d_in[1];
    const float* w_s  = (const float*)d_in[2];
    const float* b_s  = (const float*)d_in[3];
    const float* g_s  = (const float*)d_in[4];
    const float* be_s = (const float*)d_in[5];
    const float* w_y  = (const float*)d_in[6];
    const float* b_y  = (const float*)d_in[7];
    const float* g_y  = (const float*)d_in[8];
    const float* be_y = (const float*)d_in[9];
    const float* Wq   = (const float*)d_in[10];
    const float* Wk   = (const float*)d_in[11];
    const float* Wv   = (const float*)d_in[12];
    const float* w_o  = (const float*)d_in[13];
    const float* b_o  = (const float*)d_in[14];
    const float* g_o  = (const float*)d_in[15];
    const float* be_o = (const float*)d_in[16];
    const float* w3   = (const float*)d_in[17];
    const float* b3   = (const float*)d_in[18];
    const float* w_y2 = (const float*)d_in[19];
    const float* b_y2 = (const float*)d_in[20];
    const float* g_y2 = (const float*)d_in[21];
    const float* be_y2= (const float*)d_in[22];
    float* out = (float*)d_out;

    float* ws = (float*)d_ws;
    float* S_pe   = ws;                       // 2*48*4096   = 393216
    float* Y_pe   = ws + 393216;              // 2*96*4096   = 786432
    float* S1     = ws + 1179648;             // (B,N,48)
    float* Y1     = ws + 1572864;
    float* Qb     = ws + 1966080;
    float* Kb     = ws + 2359296;
    float* Vb     = ws + 2752512;
    float* pm     = ws + 3145728;             // 2*16*4096
    float* ps     = ws + 3276800;
    float* colm   = ws + 3407872;             // 2*4096
    float* colinv = ws + 3416064;
    float* xpart  = ws + 3424256;             // 2*8*4096*48 = 3145728
    float* Y3     = ws + 6569984;             // 2*96*4096

    // 1. positional encodings
    pe_add_kernel<<<1536, 256, 0, stream>>>(S, S_pe, 48, 16);
    pe_add_kernel<<<3072, 256, 0, stream>>>(Y, Y_pe, 96, 32);
    // 2. projections (conv1x1 + BN + ReLU) -> (B,N,48)
    proj_kernel<48, 48><<<32, 256, 0, stream>>>(S_pe, w_s, b_s, g_s, be_s, S1);
    proj_kernel<96, 48><<<32, 256, 0, stream>>>(Y_pe, w_y, b_y, g_y, be_y, Y1);
    // 3. Q, K, V
    rmul48_kernel<<<32, 256, 0, stream>>>(Y1, Wq, Qb);
    rmul48_kernel<<<32, 256, 0, stream>>>(Y1, Wk, Kb);
    rmul48_kernel<<<32, 256, 0, stream>>>(S1, Wv, Vb);
    // 4. attention column-softmax stats (softmax over q, per key k)
    attn_stats_kernel<<<512, 256, 0, stream>>>(Qb, Kb, pm, ps);
    stats_reduce_kernel<<<32, 256, 0, stream>>>(pm, ps, colm, colinv);
    // 5. x = A @ V partials
    attn_pv_kernel<<<256, 256, 0, stream>>>(Qb, Kb, Vb, colm, colinv, xpart);
    // 6. 3x3x3 conv branch
    conv3d_kernel<<<768, 256, 0, stream>>>(Y_pe, w3, b3, Y3);
    // 7. outputs
    z_out_kernel<<<32, 256, 0, stream>>>(xpart, w_o, b_o, g_o, be_o, S_pe, out);
    y2_out_kernel<<<32, 256, 0, stream>>>(Y3, w_y2, b_y2, g_y2, be_y2, out);
}

// Round 2
// 769.774 us; speedup vs baseline: 1.5208x; 1.5208x over previous
//
#include <hip/hip_runtime.h>
#include <hip/hip_bf16.h>

#define NPOS 4096
#define BB 2
#define KS 4   // k-split for PV pass
#define QS 8   // q-split for stats pass

typedef short v4s __attribute__((ext_vector_type(4)));
typedef float v4f __attribute__((ext_vector_type(4)));

static __device__ __forceinline__ unsigned short f2bf(float f) {
    unsigned int u = __float_as_uint(f);
    return (unsigned short)((u + 0x7fffu + ((u >> 16) & 1u)) >> 16);
}

__device__ __forceinline__ float pe_val(int C, int c, int ch, int h, int w) {
    int blk = ch / c;
    int j = ch - blk * c;
    int half = c >> 1;
    int jj = (j < half) ? j : j - half;
    float freq = __expf(-(2.0f * jj / (float)c) * 9.210340371976184f); // ln(10000)
    int pos = (blk < 2) ? h : w;   // torch-broadcast quirk: blocks 0,1 -> y(=h), block 2 -> z(=w)
    float s = (float)pos * freq;
    return (j < half) ? __sinf(s) : __cosf(s);
}

__global__ void pe_add_kernel(const float* __restrict__ in, float* __restrict__ out, int C, int c) {
    int idx = blockIdx.x * 256 + threadIdx.x;
    int total = BB * C * NPOS;
    if (idx >= total) return;
    int n = idx & 4095;
    int ch = (idx >> 12) % C;
    int h = (n >> 4) & 15;
    int w = n & 15;
    out[idx] = in[idx] + pe_val(C, c, ch, h, w);
}

// conv1x1 + BN + ReLU.  in: (B,CI,N)  ->  out: (B,N,CO)
template<int CI, int CO>
__global__ void proj_kernel(const float* __restrict__ in, const float* __restrict__ w,
                            const float* __restrict__ bias, const float* __restrict__ g,
                            const float* __restrict__ be, float* __restrict__ out) {
    __shared__ float wl[CO * CI];
    __shared__ float sb[CO], bb[CO];
    int t = threadIdx.x;
    for (int i = t; i < CO * CI; i += 256) wl[i] = w[i];
    if (t < CO) {
        float s = g[t] * rsqrtf(1.0f + 1e-5f);
        sb[t] = s; bb[t] = bias[t] * s + be[t];
    }
    __syncthreads();
    int gn = blockIdx.x * 256 + t;
    if (gn >= BB * NPOS) return;
    int b = gn >> 12; int n = gn & 4095;
    const float* ip = in + (size_t)b * CI * NPOS + n;
    float acc[CO];
#pragma unroll
    for (int o = 0; o < CO; o++) acc[o] = 0.f;
    for (int ci = 0; ci < CI; ci++) {
        float v = ip[(size_t)ci * NPOS];
#pragma unroll
        for (int o = 0; o < CO; o++) acc[o] += v * wl[o * CI + ci];
    }
    float* op = out + (size_t)gn * CO;
#pragma unroll
    for (int o = 0; o < CO; o++) {
        float z = acc[o] * sb[o] + bb[o];
        op[o] = z > 0.f ? z : 0.f;
    }
}

// out[b,n,e] = sum_d in[b,n,d] * W[d,e]  -> bf16 row-major (B,N,48)
__global__ void rmul_qk_kernel(const float* __restrict__ in, const float* __restrict__ w,
                               unsigned short* __restrict__ out) {
    __shared__ float wl[48 * 48];
    int t = threadIdx.x;
    for (int i = t; i < 48 * 48; i += 256) wl[i] = w[i];
    __syncthreads();
    int gn = blockIdx.x * 256 + t;
    if (gn >= BB * NPOS) return;
    const float* ip = in + (size_t)gn * 48;
    float acc[48];
#pragma unroll
    for (int e = 0; e < 48; e++) acc[e] = 0.f;
    for (int d = 0; d < 48; d++) {
        float v = ip[d];
#pragma unroll
        for (int e = 0; e < 48; e++) acc[e] += v * wl[d * 48 + e];
    }
    unsigned short* op = out + (size_t)gn * 48;
#pragma unroll
    for (int e = 0; e < 48; e++) op[e] = f2bf(acc[e]);
}

// out[b,e,n] = sum_d in[b,n,d] * W[d,e]  -> bf16 transposed (B,48,N)
__global__ void rmul_v_kernel(const float* __restrict__ in, const float* __restrict__ w,
                              unsigned short* __restrict__ outT) {
    __shared__ float wl[48 * 48];
    int t = threadIdx.x;
    for (int i = t; i < 48 * 48; i += 256) wl[i] = w[i];
    __syncthreads();
    int gn = blockIdx.x * 256 + t;
    if (gn >= BB * NPOS) return;
    int b = gn >> 12; int n = gn & 4095;
    const float* ip = in + (size_t)gn * 48;
    float acc[48];
#pragma unroll
    for (int e = 0; e < 48; e++) acc[e] = 0.f;
    for (int d = 0; d < 48; d++) {
        float v = ip[d];
#pragma unroll
        for (int e = 0; e < 48; e++) acc[e] += v * wl[d * 48 + e];
    }
#pragma unroll
    for (int e = 0; e < 48; e++)
        outT[((size_t)(b * 48 + e) << 12) + n] = f2bf(acc[e]);
}

// Pass 1: column (over-q) softmax stats via swapped MFMA S^T = K*Q^T.
// grid: b(2) x kb(64) x qs(QS).  4 waves; wave w owns keys [kb*64+16w, +16).
__global__ void attn_stats_mfma_kernel(const unsigned short* __restrict__ Qb,
                                       const unsigned short* __restrict__ Kb,
                                       float* __restrict__ pm, float* __restrict__ ps) {
    int bid = blockIdx.x;
    int qs = bid & (QS - 1); int kb = (bid >> 3) & 63; int b = bid >> 9;
    int t = threadIdx.x; int wv = t >> 6; int lane = t & 63;
    int lr = lane & 15, g = lane >> 4;
    const float scale = 0.14433756729740643f;
    int key = kb * 64 + wv * 16 + lr;             // A-frag row this lane loads
    const unsigned short* krow = Kb + ((size_t)(b * NPOS + key)) * 48;
    v4s ka[3];
#pragma unroll
    for (int db = 0; db < 3; db++) ka[db] = *(const v4s*)(krow + 16 * db + 4 * g);
    float m[4], s[4];
#pragma unroll
    for (int r = 0; r < 4; r++) { m[r] = -1e30f; s[r] = 0.f; }
    for (int qt = 0; qt < 512 / 16; qt++) {
        int q = qs * 512 + qt * 16 + lr;
        const unsigned short* qrow = Qb + ((size_t)(b * NPOS + q)) * 48;
        v4f acc = {0.f, 0.f, 0.f, 0.f};
#pragma unroll
        for (int db = 0; db < 3; db++)
            acc = __builtin_amdgcn_mfma_f32_16x16x16bf16_1k(
                ka[db], *(const v4s*)(qrow + 16 * db + 4 * g), acc, 0, 0, 0);
        // lane holds scores for q = qt*16+lr, keys = kb*64+16w+4g+r
#pragma unroll
        for (int r = 0; r < 4; r++) {
            float sc = acc[r] * scale;
            float mn = fmaxf(m[r], sc);
            s[r] = s[r] * __expf(m[r] - mn) + __expf(sc - mn);
            m[r] = mn;
        }
    }
    // combine over the 16 q-lanes within each lane group
#pragma unroll
    for (int off = 1; off < 16; off <<= 1) {
#pragma unroll
        for (int r = 0; r < 4; r++) {
            float mo = __shfl_xor(m[r], off);
            float so = __shfl_xor(s[r], off);
            float mn = fmaxf(m[r], mo);
            s[r] = s[r] * __expf(m[r] - mn) + so * __expf(mo - mn);
            m[r] = mn;
        }
    }
    if (lr == 0) {
        int idx = (b * QS + qs) * NPOS + kb * 64 + wv * 16 + 4 * g;
        v4f mm = {m[0], m[1], m[2], m[3]};
        v4f ss = {s[0], s[1], s[2], s[3]};
        *(v4f*)&pm[idx] = mm;
        *(v4f*)&ps[idx] = ss;
    }
}

__global__ void stats_reduce_kernel(const float* __restrict__ pm, const float* __restrict__ ps,
                                    float* __restrict__ colm, float* __restrict__ colinv) {
    int idx = blockIdx.x * 256 + threadIdx.x;
    if (idx >= BB * NPOS) return;
    int b = idx >> 12; int k = idx & 4095;
    float m = -1e30f;
    for (int qs = 0; qs < QS; qs++) m = fmaxf(m, pm[(size_t)(b * QS + qs) * NPOS + k]);
    float s = 0.f;
    for (int qs = 0; qs < QS; qs++)
        s += ps[(size_t)(b * QS + qs) * NPOS + k] * __expf(pm[(size_t)(b * QS + qs) * NPOS + k] - m);
    colm[idx] = m;
    colinv[idx] = 1.0f / s;
}

// Pass 2: x = A*V via MFMA.  grid: b(2) x qb(64) x ks(KS).  Wave w owns 16 q.
// S^T tile output fragment IS the PV A-operand fragment (swapped-MFMA chaining).
__global__ void attn_pv_mfma_kernel(const unsigned short* __restrict__ Qb,
                                    const unsigned short* __restrict__ Kb,
                                    const unsigned short* __restrict__ Vt,
                                    const float* __restrict__ colm,
                                    const float* __restrict__ colinv,
                                    float* __restrict__ xpart) {
    int bid = blockIdx.x;
    int ks = bid & (KS - 1); int qb = (bid >> 2) & 63; int b = bid >> 8;
    int t = threadIdx.x; int wv = t >> 6; int lane = t & 63;
    int lr = lane & 15, g = lane >> 4;
    const float scale = 0.14433756729740643f;
    int q0 = qb * 64 + wv * 16;
    const unsigned short* qrow = Qb + ((size_t)(b * NPOS + q0 + lr)) * 48;
    v4s qf[3];
#pragma unroll
    for (int db = 0; db < 3; db++) qf[db] = *(const v4s*)(qrow + 16 * db + 4 * g);
    v4f xacc[3];
#pragma unroll
    for (int nt = 0; nt < 3; nt++) xacc[nt] = (v4f){0.f, 0.f, 0.f, 0.f};
    for (int kt = 0; kt < 4096 / KS / 64; kt++) {
        int kb0 = ks * (4096 / KS) + kt * 64;
        v4s p[4];
#pragma unroll
        for (int tm = 0; tm < 4; tm++) {
            const unsigned short* krow = Kb + ((size_t)(b * NPOS + kb0 + 16 * tm + lr)) * 48;
            v4f acc = {0.f, 0.f, 0.f, 0.f};
#pragma unroll
            for (int db = 0; db < 3; db++)
                acc = __builtin_amdgcn_mfma_f32_16x16x16bf16_1k(
                    *(const v4s*)(krow + 16 * db + 4 * g), qf[db], acc, 0, 0, 0);
            // lane: q = q0+lr, keys = kb0+16tm+4g+r
            int kc = b * NPOS + kb0 + 16 * tm + 4 * g;
            v4f cm = *(const v4f*)&colm[kc];
            v4f ci = *(const v4f*)&colinv[kc];
            v4s pp;
#pragma unroll
            for (int r = 0; r < 4; r++)
                pp[r] = (short)f2bf(__expf(acc[r] * scale - cm[r]) * ci[r]);
            p[tm] = pp;
        }
#pragma unroll
        for (int nt = 0; nt < 3; nt++) {
            const unsigned short* vrow = Vt + ((size_t)(b * 48 + 16 * nt + lr) << 12) + kb0;
#pragma unroll
            for (int tm = 0; tm < 4; tm++)
                xacc[nt] = __builtin_amdgcn_mfma_f32_16x16x16bf16_1k(
                    p[tm], *(const v4s*)(vrow + 16 * tm + 4 * g), xacc[nt], 0, 0, 0);
        }
    }
    // lane: d = 16nt+lr, q = q0+4g+r  -> xpart[(b,ks,d,q)] float4 over q
#pragma unroll
    for (int nt = 0; nt < 3; nt++)
        *(v4f*)&xpart[(((size_t)(b * KS + ks) * 48) + 16 * nt + lr) * NPOS + q0 + 4 * g] = xacc[nt];
}

// Reduce x partials + conv1x1(w_o) + BN + ReLU, * S_pe -> out channels [0,48)
__global__ void z_out_kernel(const float* __restrict__ xpart, const float* __restrict__ w_o,
                             const float* __restrict__ b_o, const float* __restrict__ g_o,
                             const float* __restrict__ be_o, const float* __restrict__ S_pe,
                             float* __restrict__ out) {
    __shared__ float wl[48 * 48];
    __shared__ float sb[48], bb[48];
    int t = threadIdx.x;
    for (int i = t; i < 48 * 48; i += 256) wl[i] = w_o[i];
    if (t < 48) { float s = g_o[t] * rsqrtf(1.f + 1e-5f); sb[t] = s; bb[t] = b_o[t] * s + be_o[t]; }
    __syncthreads();
    int gn = blockIdx.x * 256 + t;
    if (gn >= BB * NPOS) return;
    int b = gn >> 12; int n = gn & 4095;
    float x[48];
#pragma unroll
    for (int d = 0; d < 48; d++) x[d] = 0.f;
    for (int ks = 0; ks < KS; ks++) {
        const float* p = xpart + ((size_t)(b * KS + ks) * 48) * NPOS + n;
#pragma unroll
        for (int d = 0; d < 48; d++) x[d] += p[(size_t)d * NPOS];
    }
    for (int o = 0; o < 48; o++) {
        float acc = 0.f;
#pragma unroll
        for (int d = 0; d < 48; d++) acc += wl[o * 48 + d] * x[d];
        float z = acc * sb[o] + bb[o];
        z = z > 0.f ? z : 0.f;
        out[((size_t)b * 96 + o) * NPOS + n] = z * S_pe[((size_t)b * 48 + o) * NPOS + n];
    }
}

// 3x3x3 SAME conv + b3.  grid: b(2) x co(96) x zslab(4), 256 threads = 16x16 plane.
__global__ void conv3d_kernel(const float* __restrict__ Y_pe, const float* __restrict__ w3,
                              const float* __restrict__ b3, float* __restrict__ Y3) {
    int bid = blockIdx.x;
    int zs = bid & 3; int co = (bid >> 2) % 96; int b = bid / (96 * 4);
    int t = threadIdx.x;
    int h = t >> 4; int w = t & 15;
    __shared__ float wl[96 * 27];
    __shared__ float tile[6 * 18 * 18];
    for (int i = t; i < 96 * 27; i += 256) wl[i] = w3[(size_t)co * 96 * 27 + i];
    float acc[4];
#pragma unroll
    for (int i = 0; i < 4; i++) acc[i] = 0.f;
    int z0 = zs * 4;
    for (int ci = 0; ci < 96; ci++) {
        __syncthreads();
        for (int i = t; i < 6 * 18 * 18; i += 256) {
            int tz = i / 324; int r = i - tz * 324; int th = r / 18; int tw = r - th * 18;
            int gz = z0 + tz - 1, gh = th - 1, gw = tw - 1;
            float v = 0.f;
            if (gz >= 0 && gz < 16 && gh >= 0 && gh < 16 && gw >= 0 && gw < 16)
                v = Y_pe[(((size_t)b * 96 + ci) * 4096) + gz * 256 + gh * 16 + gw];
            tile[i] = v;
        }
        __syncthreads();
        const float* wp = &wl[ci * 27];
#pragma unroll
        for (int kh = 0; kh < 3; kh++)
#pragma unroll
            for (int kw = 0; kw < 3; kw++) {
                float col[6];
#pragma unroll
                for (int tz = 0; tz < 6; tz++) col[tz] = tile[tz * 324 + (h + kh) * 18 + (w + kw)];
#pragma unroll
                for (int kd = 0; kd < 3; kd++) {
                    float wv = wp[kd * 9 + kh * 3 + kw];
#pragma unroll
                    for (int zi = 0; zi < 4; zi++) acc[zi] += wv * col[zi + kd];
                }
            }
    }
    float bv = b3[co];
#pragma unroll
    for (int zi = 0; zi < 4; zi++)
        Y3[(((size_t)b * 96 + co) * 4096) + (z0 + zi) * 256 + h * 16 + w] = acc[zi] + bv;
}

// conv1x1(w_y2) + BN + ReLU on Y3 -> out channels [48,96)
__global__ void y2_out_kernel(const float* __restrict__ Y3, const float* __restrict__ w_y2,
                              const float* __restrict__ b_y2, const float* __restrict__ g_y2,
                              const float* __restrict__ be_y2, float* __restrict__ out) {
    __shared__ float wl[48 * 96];
    __shared__ float sb[48], bb[48];
    int t = threadIdx.x;
    for (int i = t; i < 48 * 96; i += 256) wl[i] = w_y2[i];
    if (t < 48) { float s = g_y2[t] * rsqrtf(1.f + 1e-5f); sb[t] = s; bb[t] = b_y2[t] * s + be_y2[t]; }
    __syncthreads();
    int gn = blockIdx.x * 256 + t;
    if (gn >= BB * NPOS) return;
    int b = gn >> 12; int n = gn & 4095;
    const float* ip = Y3 + (size_t)b * 96 * NPOS + n;
    float acc[48];
#pragma unroll
    for (int o = 0; o < 48; o++) acc[o] = 0.f;
    for (int ci = 0; ci < 96; ci++) {
        float v = ip[(size_t)ci * NPOS];
#pragma unroll
        for (int o = 0; o < 48; o++) acc[o] += v * wl[o * 96 + ci];
    }
    for (int o = 0; o < 48; o++) {
        float z = acc[o] * sb[o] + bb[o];
        out[((size_t)b * 96 + 48 + o) * NPOS + n] = z > 0.f ? z : 0.f;
    }
}

extern "C" void kernel_launch(void* const* d_in, const int* in_sizes, int n_in,
                              void* d_out, int out_size, void* d_ws, size_t ws_size,
                              hipStream_t stream) {
    const float* Y    = (const float*)d_in[0];
    const float* S    = (const float*)d_in[1];
    const float* w_s  = (const float*)d_in[2];
    const float* b_s  = (const float*)d_in[3];
    const float* g_s  = (const float*)d_in[4];
    const float* be_s = (const float*)d_in[5];
    const float* w_y  = (const float*)d_in[6];
    const float* b_y  = (const float*)d_in[7];
    const float* g_y  = (const float*)d_in[8];
    const float* be_y = (const float*)d_in[9];
    const float* Wq   = (const float*)d_in[10];
    const float* Wk   = (const float*)d_in[11];
    const float* Wv   = (const float*)d_in[12];
    const float* w_o  = (const float*)d_in[13];
    const float* b_o  = (const float*)d_in[14];
    const float* g_o  = (const float*)d_in[15];
    const float* be_o = (const float*)d_in[16];
    const float* w3   = (const float*)d_in[17];
    const float* b3   = (const float*)d_in[18];
    const float* w_y2 = (const float*)d_in[19];
    const float* b_y2 = (const float*)d_in[20];
    const float* g_y2 = (const float*)d_in[21];
    const float* be_y2= (const float*)d_in[22];
    float* out = (float*)d_out;

    float* ws = (float*)d_ws;
    float* S_pe   = ws;                       // 393216
    float* Y_pe   = ws + 393216;              // 786432
    float* S1     = ws + 1179648;             // 393216
    float* Y1     = ws + 1572864;             // 393216
    unsigned short* Qb = (unsigned short*)(ws + 1966080);   // 2*4096*48 bf16 = 196608 f
    unsigned short* Kb = (unsigned short*)(ws + 2162688);   // 196608 f
    unsigned short* Vt = (unsigned short*)(ws + 2359296);   // 196608 f
    float* pm     = ws + 2555904;             // 2*QS*4096 = 65536
    float* ps     = ws + 2621440;             // 65536
    float* colm   = ws + 2686976;             // 8192
    float* colinv = ws + 2695168;             // 8192
    float* xpart  = ws + 2703360;             // 2*KS*48*4096 = 1572864
    float* Y3     = ws + 4276224;             // 786432

    // 1. positional encodings
    pe_add_kernel<<<1536, 256, 0, stream>>>(S, S_pe, 48, 16);
    pe_add_kernel<<<3072, 256, 0, stream>>>(Y, Y_pe, 96, 32);
    // 2. projections (conv1x1 + BN + ReLU) -> (B,N,48)
    proj_kernel<48, 48><<<32, 256, 0, stream>>>(S_pe, w_s, b_s, g_s, be_s, S1);
    proj_kernel<96, 48><<<32, 256, 0, stream>>>(Y_pe, w_y, b_y, g_y, be_y, Y1);
    // 3. Q, K row-major bf16; V transposed bf16
    rmul_qk_kernel<<<32, 256, 0, stream>>>(Y1, Wq, Qb);
    rmul_qk_kernel<<<32, 256, 0, stream>>>(Y1, Wk, Kb);
    rmul_v_kernel<<<32, 256, 0, stream>>>(S1, Wv, Vt);
    // 4. column-softmax stats (softmax over q, per key k), MFMA
    attn_stats_mfma_kernel<<<BB * 64 * QS, 256, 0, stream>>>(Qb, Kb, pm, ps);
    stats_reduce_kernel<<<32, 256, 0, stream>>>(pm, ps, colm, colinv);
    // 5. x = A @ V partials, MFMA
    attn_pv_mfma_kernel<<<BB * 64 * KS, 256, 0, stream>>>(Qb, Kb, Vt, colm, colinv, xpart);
    // 6. 3x3x3 conv branch
    conv3d_kernel<<<768, 256, 0, stream>>>(Y_pe, w3, b3, Y3);
    // 7. outputs
    z_out_kernel<<<32, 256, 0, stream>>>(xpart, w_o, b_o, g_o, be_o, S_pe, out);
    y2_out_kernel<<<32, 256, 0, stream>>>(Y3, w_y2, b_y2, g_y2, be_y2, out);
}

// Round 3
// 430.800 us; speedup vs baseline: 2.7175x; 1.7868x over previous
//
#include <hip/hip_runtime.h>
#include <hip/hip_bf16.h>

#define NPOS 4096
#define BB 2
#define KS 4   // k-split for PV pass
#define QS 8   // q-split for stats pass

typedef short v4s __attribute__((ext_vector_type(4)));
typedef float v4f __attribute__((ext_vector_type(4)));
typedef unsigned short ushort_t;

static __device__ __forceinline__ unsigned short f2bf(float f) {
    unsigned int u = __float_as_uint(f);
    return (unsigned short)((u + 0x7fffu + ((u >> 16) & 1u)) >> 16);
}

__device__ __forceinline__ float pe_val(int C, int c, int ch, int h, int w) {
    int blk = ch / c;
    int j = ch - blk * c;
    int half = c >> 1;
    int jj = (j < half) ? j : j - half;
    float freq = __expf(-(2.0f * jj / (float)c) * 9.210340371976184f); // ln(10000)
    int pos = (blk < 2) ? h : w;   // torch-broadcast quirk: blocks 0,1 -> y(=h), block 2 -> z(=w)
    float s = (float)pos * freq;
    return (j < half) ? __sinf(s) : __cosf(s);
}

__global__ void pe_add_kernel(const float* __restrict__ in, float* __restrict__ out, int C, int c) {
    int idx = blockIdx.x * 256 + threadIdx.x;
    int total = BB * C * NPOS;
    if (idx >= total) return;
    int n = idx & 4095;
    int ch = (idx >> 12) % C;
    int h = (n >> 4) & 15;
    int w = n & 15;
    out[idx] = in[idx] + pe_val(C, c, ch, h, w);
}

// conv1x1 + BN + ReLU.  in: (B,CI,N)  ->  out: (B,N,CO)
template<int CI, int CO>
__global__ void proj_kernel(const float* __restrict__ in, const float* __restrict__ w,
                            const float* __restrict__ bias, const float* __restrict__ g,
                            const float* __restrict__ be, float* __restrict__ out) {
    __shared__ float wl[CO * CI];
    __shared__ float sb[CO], bb[CO];
    int t = threadIdx.x;
    for (int i = t; i < CO * CI; i += 256) wl[i] = w[i];
    if (t < CO) {
        float s = g[t] * rsqrtf(1.0f + 1e-5f);
        sb[t] = s; bb[t] = bias[t] * s + be[t];
    }
    __syncthreads();
    int gn = blockIdx.x * 256 + t;
    if (gn >= BB * NPOS) return;
    int b = gn >> 12; int n = gn & 4095;
    const float* ip = in + (size_t)b * CI * NPOS + n;
    float acc[CO];
#pragma unroll
    for (int o = 0; o < CO; o++) acc[o] = 0.f;
    for (int ci = 0; ci < CI; ci++) {
        float v = ip[(size_t)ci * NPOS];
#pragma unroll
        for (int o = 0; o < CO; o++) acc[o] += v * wl[o * CI + ci];
    }
    float* op = out + (size_t)gn * CO;
#pragma unroll
    for (int o = 0; o < CO; o++) {
        float z = acc[o] * sb[o] + bb[o];
        op[o] = z > 0.f ? z : 0.f;
    }
}

// Q,K,V in one launch. blocks 0-31: Q (row-major), 32-63: K (row-major), 64-95: V (transposed)
__global__ void qkv_kernel(const float* __restrict__ Y1, const float* __restrict__ S1,
                           const float* __restrict__ Wq, const float* __restrict__ Wk,
                           const float* __restrict__ Wv, ushort_t* __restrict__ Qb,
                           ushort_t* __restrict__ Kb, ushort_t* __restrict__ Vt) {
    int grp = blockIdx.x >> 5;
    int blk = blockIdx.x & 31;
    const float* in = (grp == 2) ? S1 : Y1;
    const float* w = (grp == 0) ? Wq : (grp == 1) ? Wk : Wv;
    __shared__ float wl[48 * 48];
    int t = threadIdx.x;
    for (int i = t; i < 48 * 48; i += 256) wl[i] = w[i];
    __syncthreads();
    int gn = blk * 256 + t;
    const float* ip = in + (size_t)gn * 48;
    float acc[48];
#pragma unroll
    for (int e = 0; e < 48; e++) acc[e] = 0.f;
    for (int d = 0; d < 48; d++) {
        float v = ip[d];
#pragma unroll
        for (int e = 0; e < 48; e++) acc[e] += v * wl[d * 48 + e];
    }
    if (grp < 2) {
        ushort_t* op = (grp == 0 ? Qb : Kb) + (size_t)gn * 48;
#pragma unroll
        for (int e = 0; e < 48; e++) op[e] = f2bf(acc[e]);
    } else {
        int b = gn >> 12; int n = gn & 4095;
#pragma unroll
        for (int e = 0; e < 48; e++)
            Vt[((size_t)(b * 48 + e) << 12) + n] = f2bf(acc[e]);
    }
}

// Pass 1: column (over-q) softmax stats via swapped MFMA S^T = K*Q^T.
__global__ void attn_stats_mfma_kernel(const ushort_t* __restrict__ Qb,
                                       const ushort_t* __restrict__ Kb,
                                       float* __restrict__ pm, float* __restrict__ ps) {
    int bid = blockIdx.x;
    int qs = bid & (QS - 1); int kb = (bid >> 3) & 63; int b = bid >> 9;
    int t = threadIdx.x; int wv = t >> 6; int lane = t & 63;
    int lr = lane & 15, g = lane >> 4;
    const float scale = 0.14433756729740643f;
    int key = kb * 64 + wv * 16 + lr;
    const ushort_t* krow = Kb + ((size_t)(b * NPOS + key)) * 48;
    v4s ka[3];
#pragma unroll
    for (int db = 0; db < 3; db++) ka[db] = *(const v4s*)(krow + 16 * db + 4 * g);
    float m[4], s[4];
#pragma unroll
    for (int r = 0; r < 4; r++) { m[r] = -1e30f; s[r] = 0.f; }
    for (int qt = 0; qt < 512 / 16; qt++) {
        int q = qs * 512 + qt * 16 + lr;
        const ushort_t* qrow = Qb + ((size_t)(b * NPOS + q)) * 48;
        v4f acc = {0.f, 0.f, 0.f, 0.f};
#pragma unroll
        for (int db = 0; db < 3; db++)
            acc = __builtin_amdgcn_mfma_f32_16x16x16bf16_1k(
                ka[db], *(const v4s*)(qrow + 16 * db + 4 * g), acc, 0, 0, 0);
#pragma unroll
        for (int r = 0; r < 4; r++) {
            float sc = acc[r] * scale;
            float mn = fmaxf(m[r], sc);
            s[r] = s[r] * __expf(m[r] - mn) + __expf(sc - mn);
            m[r] = mn;
        }
    }
#pragma unroll
    for (int off = 1; off < 16; off <<= 1) {
#pragma unroll
        for (int r = 0; r < 4; r++) {
            float mo = __shfl_xor(m[r], off);
            float so = __shfl_xor(s[r], off);
            float mn = fmaxf(m[r], mo);
            s[r] = s[r] * __expf(m[r] - mn) + so * __expf(mo - mn);
            m[r] = mn;
        }
    }
    if (lr == 0) {
        int idx = (b * QS + qs) * NPOS + kb * 64 + wv * 16 + 4 * g;
        v4f mm = {m[0], m[1], m[2], m[3]};
        v4f ss = {s[0], s[1], s[2], s[3]};
        *(v4f*)&pm[idx] = mm;
        *(v4f*)&ps[idx] = ss;
    }
}

__global__ void stats_reduce_kernel(const float* __restrict__ pm, const float* __restrict__ ps,
                                    float* __restrict__ colm, float* __restrict__ colinv) {
    int idx = blockIdx.x * 256 + threadIdx.x;
    if (idx >= BB * NPOS) return;
    int b = idx >> 12; int k = idx & 4095;
    float m = -1e30f;
    for (int qs = 0; qs < QS; qs++) m = fmaxf(m, pm[(size_t)(b * QS + qs) * NPOS + k]);
    float s = 0.f;
    for (int qs = 0; qs < QS; qs++)
        s += ps[(size_t)(b * QS + qs) * NPOS + k] * __expf(pm[(size_t)(b * QS + qs) * NPOS + k] - m);
    colm[idx] = m;
    colinv[idx] = 1.0f / s;
}

// Pass 2: x = A*V via MFMA, swapped-MFMA chaining (S^T frag == PV A-frag).
__global__ void attn_pv_mfma_kernel(const ushort_t* __restrict__ Qb,
                                    const ushort_t* __restrict__ Kb,
                                    const ushort_t* __restrict__ Vt,
                                    const float* __restrict__ colm,
                                    const float* __restrict__ colinv,
                                    float* __restrict__ xpart) {
    int bid = blockIdx.x;
    int ks = bid & (KS - 1); int qb = (bid >> 2) & 63; int b = bid >> 8;
    int t = threadIdx.x; int wv = t >> 6; int lane = t & 63;
    int lr = lane & 15, g = lane >> 4;
    const float scale = 0.14433756729740643f;
    int q0 = qb * 64 + wv * 16;
    const ushort_t* qrow = Qb + ((size_t)(b * NPOS + q0 + lr)) * 48;
    v4s qf[3];
#pragma unroll
    for (int db = 0; db < 3; db++) qf[db] = *(const v4s*)(qrow + 16 * db + 4 * g);
    v4f xacc[3];
#pragma unroll
    for (int nt = 0; nt < 3; nt++) xacc[nt] = (v4f){0.f, 0.f, 0.f, 0.f};
    for (int kt = 0; kt < 4096 / KS / 64; kt++) {
        int kb0 = ks * (4096 / KS) + kt * 64;
        v4s p[4];
#pragma unroll
        for (int tm = 0; tm < 4; tm++) {
            const ushort_t* krow = Kb + ((size_t)(b * NPOS + kb0 + 16 * tm + lr)) * 48;
            v4f acc = {0.f, 0.f, 0.f, 0.f};
#pragma unroll
            for (int db = 0; db < 3; db++)
                acc = __builtin_amdgcn_mfma_f32_16x16x16bf16_1k(
                    *(const v4s*)(krow + 16 * db + 4 * g), qf[db], acc, 0, 0, 0);
            int kc = b * NPOS + kb0 + 16 * tm + 4 * g;
            v4f cm = *(const v4f*)&colm[kc];
            v4f ci = *(const v4f*)&colinv[kc];
            v4s pp;
#pragma unroll
            for (int r = 0; r < 4; r++)
                pp[r] = (short)f2bf(__expf(acc[r] * scale - cm[r]) * ci[r]);
            p[tm] = pp;
        }
#pragma unroll
        for (int nt = 0; nt < 3; nt++) {
            const ushort_t* vrow = Vt + ((size_t)(b * 48 + 16 * nt + lr) << 12) + kb0;
#pragma unroll
            for (int tm = 0; tm < 4; tm++)
                xacc[nt] = __builtin_amdgcn_mfma_f32_16x16x16bf16_1k(
                    p[tm], *(const v4s*)(vrow + 16 * tm + 4 * g), xacc[nt], 0, 0, 0);
        }
    }
#pragma unroll
    for (int nt = 0; nt < 3; nt++)
        *(v4f*)&xpart[(((size_t)(b * KS + ks) * 48) + 16 * nt + lr) * NPOS + q0 + 4 * g] = xacc[nt];
}

// Reduce x partials + conv1x1(w_o) + BN + ReLU, * S_pe -> out channels [0,48)
__global__ void z_out_kernel(const float* __restrict__ xpart, const float* __restrict__ w_o,
                             const float* __restrict__ b_o, const float* __restrict__ g_o,
                             const float* __restrict__ be_o, const float* __restrict__ S_pe,
                             float* __restrict__ out) {
    __shared__ float wl[48 * 48];
    __shared__ float sb[48], bb[48];
    int t = threadIdx.x;
    for (int i = t; i < 48 * 48; i += 256) wl[i] = w_o[i];
    if (t < 48) { float s = g_o[t] * rsqrtf(1.f + 1e-5f); sb[t] = s; bb[t] = b_o[t] * s + be_o[t]; }
    __syncthreads();
    int gn = blockIdx.x * 256 + t;
    if (gn >= BB * NPOS) return;
    int b = gn >> 12; int n = gn & 4095;
    float x[48];
#pragma unroll
    for (int d = 0; d < 48; d++) x[d] = 0.f;
    for (int ks = 0; ks < KS; ks++) {
        const float* p = xpart + ((size_t)(b * KS + ks) * 48) * NPOS + n;
#pragma unroll
        for (int d = 0; d < 48; d++) x[d] += p[(size_t)d * NPOS];
    }
    for (int o = 0; o < 48; o++) {
        float acc = 0.f;
#pragma unroll
        for (int d = 0; d < 48; d++) acc += wl[o * 48 + d] * x[d];
        float z = acc * sb[o] + bb[o];
        z = z > 0.f ? z : 0.f;
        out[((size_t)b * 96 + o) * NPOS + n] = z * S_pe[((size_t)b * 48 + o) * NPOS + n];
    }
}

// ---- conv3d via implicit-GEMM MFMA ----

__global__ void zero_kernel(float* __restrict__ p, int n4) {
    int i = blockIdx.x * 256 + threadIdx.x;
    if (i < n4) ((float4*)p)[i] = make_float4(0.f, 0.f, 0.f, 0.f);
}

// Y_pe (B,96,4096) fp32 -> Y_pad (B,18,18,18,96) bf16 interior (halo pre-zeroed)
__global__ void pad_build_kernel(const float* __restrict__ Y_pe, ushort_t* __restrict__ Ypad) {
    int idx = blockIdx.x * 256 + threadIdx.x;   // over B * 24 * 4096
    if (idx >= BB * 24 * 4096) return;
    int n = idx & 4095;
    int ci4 = (idx >> 12) % 24;
    int b = idx / (24 * 4096);
    int z = n >> 8, h = (n >> 4) & 15, w = n & 15;
    ushort_t pk[4];
#pragma unroll
    for (int j = 0; j < 4; j++)
        pk[j] = f2bf(Y_pe[((size_t)(b * 96 + ci4 * 4 + j) << 12) + n]);
    size_t dst = ((((size_t)(b * 18 + z + 1) * 18) + h + 1) * 18 + w + 1) * 96 + ci4 * 4;
    *(v4s*)&Ypad[dst] = *(v4s*)pk;
}

// w3 (96co, 96ci, 27tap) fp32 -> wr [27][96co][96ci] bf16
__global__ void w3_repack_kernel(const float* __restrict__ w3, ushort_t* __restrict__ wr) {
    int idx = blockIdx.x * 256 + threadIdx.x;
    if (idx >= 27 * 96 * 96) return;
    int ci = idx % 96;
    int t2 = idx / 96;
    int co = t2 % 96;
    int tap = t2 / 96;
    wr[idx] = f2bf(w3[(size_t)(co * 96 + ci) * 27 + tap]);
}

// out(8192 pos x 96 co) += shifted-in x w, 27 taps, ci=96.  16x16x16 MFMA.
// grid 768 x 256.  wave handles 16 w-positions (one (z,h) row) x 16 co.
__global__ void conv3d_mfma_kernel(const ushort_t* __restrict__ Ypad,
                                   const ushort_t* __restrict__ wr,
                                   const float* __restrict__ b3,
                                   float* __restrict__ Y3) {
    int bid = blockIdx.x;
    int b = bid / 384;
    int r = bid % 384;
    int cot = r % 6;
    int zhq = r / 6;                 // 0..63
    int t = threadIdx.x; int wv = t >> 6; int lane = t & 63;
    int z = zhq >> 2;
    int h = (zhq & 3) * 4 + wv;
    int lr = lane & 15, g4 = (lane >> 4) * 4;
    float bv = b3[cot * 16 + lr];
    v4f acc = {bv, bv, bv, bv};
    for (int kd = 0; kd < 3; kd++) {
        for (int kh = 0; kh < 3; kh++) {
            const ushort_t* arow = Ypad + (((size_t)(b * 18 + z + kd) * 18 + h + kh) * 18 + lr) * 96 + g4;
            int tap0 = (kd * 3 + kh) * 3;
#pragma unroll
            for (int kw = 0; kw < 3; kw++) {
                const ushort_t* abase = arow + (size_t)kw * 96;
                const ushort_t* bbase = wr + ((size_t)((tap0 + kw) * 96 + cot * 16 + lr)) * 96 + g4;
#pragma unroll
                for (int cich = 0; cich < 6; cich++)
                    acc = __builtin_amdgcn_mfma_f32_16x16x16bf16_1k(
                        *(const v4s*)(abase + cich * 16),
                        *(const v4s*)(bbase + cich * 16), acc, 0, 0, 0);
            }
        }
    }
    // D: col(lane&15)=co offset, row(4g+r)=w position -> contiguous float4 in Y3
    *(v4f*)&Y3[((size_t)(b * 96 + cot * 16 + lr) << 12) + z * 256 + h * 16 + g4] = acc;
}

// conv1x1(w_y2) + BN + ReLU on Y3 -> out channels [48,96)
__global__ void y2_out_kernel(const float* __restrict__ Y3, const float* __restrict__ w_y2,
                              const float* __restrict__ b_y2, const float* __restrict__ g_y2,
                              const float* __restrict__ be_y2, float* __restrict__ out) {
    __shared__ float wl[48 * 96];
    __shared__ float sb[48], bb[48];
    int t = threadIdx.x;
    for (int i = t; i < 48 * 96; i += 256) wl[i] = w_y2[i];
    if (t < 48) { float s = g_y2[t] * rsqrtf(1.f + 1e-5f); sb[t] = s; bb[t] = b_y2[t] * s + be_y2[t]; }
    __syncthreads();
    int gn = blockIdx.x * 256 + t;
    if (gn >= BB * NPOS) return;
    int b = gn >> 12; int n = gn & 4095;
    const float* ip = Y3 + (size_t)b * 96 * NPOS + n;
    float acc[48];
#pragma unroll
    for (int o = 0; o < 48; o++) acc[o] = 0.f;
    for (int ci = 0; ci < 96; ci++) {
        float v = ip[(size_t)ci * NPOS];
#pragma unroll
        for (int o = 0; o < 48; o++) acc[o] += v * wl[o * 96 + ci];
    }
    for (int o = 0; o < 48; o++) {
        float z = acc[o] * sb[o] + bb[o];
        out[((size_t)b * 96 + 48 + o) * NPOS + n] = z > 0.f ? z : 0.f;
    }
}

extern "C" void kernel_launch(void* const* d_in, const int* in_sizes, int n_in,
                              void* d_out, int out_size, void* d_ws, size_t ws_size,
                              hipStream_t stream) {
    const float* Y    = (const float*)d_in[0];
    const float* S    = (const float*)d_in[1];
    const float* w_s  = (const float*)d_in[2];
    const float* b_s  = (const float*)d_in[3];
    const float* g_s  = (const float*)d_in[4];
    const float* be_s = (const float*)d_in[5];
    const float* w_y  = (const float*)d_in[6];
    const float* b_y  = (const float*)d_in[7];
    const float* g_y  = (const float*)d_in[8];
    const float* be_y = (const float*)d_in[9];
    const float* Wq   = (const float*)d_in[10];
    const float* Wk   = (const float*)d_in[11];
    const float* Wv   = (const float*)d_in[12];
    const float* w_o  = (const float*)d_in[13];
    const float* b_o  = (const float*)d_in[14];
    const float* g_o  = (const float*)d_in[15];
    const float* be_o = (const float*)d_in[16];
    const float* w3   = (const float*)d_in[17];
    const float* b3   = (const float*)d_in[18];
    const float* w_y2 = (const float*)d_in[19];
    const float* b_y2 = (const float*)d_in[20];
    const float* g_y2 = (const float*)d_in[21];
    const float* be_y2= (const float*)d_in[22];
    float* out = (float*)d_out;

    float* ws = (float*)d_ws;
    float* S_pe   = ws;                        // 393216
    float* Y_pe   = ws + 393216;               // 786432
    float* S1     = ws + 1179648;              // 393216
    float* Y1     = ws + 1572864;              // 393216
    ushort_t* Qb  = (ushort_t*)(ws + 1966080); // 196608 f
    ushort_t* Kb  = (ushort_t*)(ws + 2162688); // 196608 f
    ushort_t* Vt  = (ushort_t*)(ws + 2359296); // 196608 f
    float* pm     = ws + 2555904;              // 65536
    float* ps     = ws + 2621440;              // 65536
    float* colm   = ws + 2686976;              // 8192
    float* colinv = ws + 2695168;              // 8192
    float* xpart  = ws + 2703360;              // 1572864
    float* Y3     = ws + 4276224;              // 786432
    ushort_t* Ypad= (ushort_t*)(ws + 5062656); // 2*5832*96 bf16 = 559872 f
    ushort_t* wr  = (ushort_t*)(ws + 5622528); // 27*96*96 bf16 = 124416 f

    // conv3d prep (independent of attention path)
    zero_kernel<<<547, 256, 0, stream>>>((float*)Ypad, 139968);
    w3_repack_kernel<<<972, 256, 0, stream>>>(w3, wr);
    // 1. positional encodings
    pe_add_kernel<<<1536, 256, 0, stream>>>(S, S_pe, 48, 16);
    pe_add_kernel<<<3072, 256, 0, stream>>>(Y, Y_pe, 96, 32);
    // conv3d input pad (bf16)
    pad_build_kernel<<<768, 256, 0, stream>>>(Y_pe, Ypad);
    // 2. projections (conv1x1 + BN + ReLU) -> (B,N,48)
    proj_kernel<48, 48><<<32, 256, 0, stream>>>(S_pe, w_s, b_s, g_s, be_s, S1);
    proj_kernel<96, 48><<<32, 256, 0, stream>>>(Y_pe, w_y, b_y, g_y, be_y, Y1);
    // 3. Q, K row-major bf16; V transposed bf16 (one launch)
    qkv_kernel<<<96, 256, 0, stream>>>(Y1, S1, Wq, Wk, Wv, Qb, Kb, Vt);
    // 4. column-softmax stats (softmax over q, per key k), MFMA
    attn_stats_mfma_kernel<<<BB * 64 * QS, 256, 0, stream>>>(Qb, Kb, pm, ps);
    stats_reduce_kernel<<<32, 256, 0, stream>>>(pm, ps, colm, colinv);
    // 5. x = A @ V partials, MFMA
    attn_pv_mfma_kernel<<<BB * 64 * KS, 256, 0, stream>>>(Qb, Kb, Vt, colm, colinv, xpart);
    // 6. 3x3x3 conv branch, implicit-GEMM MFMA
    conv3d_mfma_kernel<<<768, 256, 0, stream>>>(Ypad, wr, b3, Y3);
    // 7. outputs
    z_out_kernel<<<32, 256, 0, stream>>>(xpart, w_o, b_o, g_o, be_o, S_pe, out);
    y2_out_kernel<<<32, 256, 0, stream>>>(Y3, w_y2, b_y2, g_y2, be_y2, out);
}

// Round 4
// 223.787 us; speedup vs baseline: 5.2313x; 1.9250x over previous
//
#include <hip/hip_runtime.h>
#include <hip/hip_bf16.h>

#define NPOS 4096
#define BB 2
#define KS 4   // k-split for PV pass
#define QS 8   // q-split for stats pass

typedef short v4s __attribute__((ext_vector_type(4)));
typedef float v4f __attribute__((ext_vector_type(4)));
typedef unsigned short ushort_t;

static __device__ __forceinline__ unsigned short f2bf(float f) {
    unsigned int u = __float_as_uint(f);
    return (unsigned short)((u + 0x7fffu + ((u >> 16) & 1u)) >> 16);
}

__device__ __forceinline__ float pe_val(int C, int c, int ch, int h, int w) {
    int blk = ch / c;
    int j = ch - blk * c;
    int half = c >> 1;
    int jj = (j < half) ? j : j - half;
    float freq = __expf(-(2.0f * jj / (float)c) * 9.210340371976184f); // ln(10000)
    int pos = (blk < 2) ? h : w;   // torch-broadcast quirk: blocks 0,1 -> y(=h), block 2 -> z(=w)
    float s = (float)pos * freq;
    return (j < half) ? __sinf(s) : __cosf(s);
}

__global__ void pe_add_kernel(const float* __restrict__ in, float* __restrict__ out, int C, int c) {
    int idx = blockIdx.x * 256 + threadIdx.x;
    int total = BB * C * NPOS;
    if (idx >= total) return;
    int n = idx & 4095;
    int ch = (idx >> 12) % C;
    int h = (n >> 4) & 15;
    int w = n & 15;
    out[idx] = in[idx] + pe_val(C, c, ch, h, w);
}

// conv1x1 + BN + ReLU, co-split x8.  in: (B,CI,N) -> out: (B,N,48)
// grid = 32 pos-chunks * 8 co-chunks
template<int CI>
__global__ void proj_kernel(const float* __restrict__ in, const float* __restrict__ w,
                            const float* __restrict__ bias, const float* __restrict__ g,
                            const float* __restrict__ be, float* __restrict__ out) {
    int pc = blockIdx.x >> 3, cc = blockIdx.x & 7;
    int o0 = cc * 6;
    __shared__ float wl[6 * CI];
    __shared__ float sb[6], bb[6];
    int t = threadIdx.x;
    for (int i = t; i < 6 * CI; i += 256) {
        int o = i / CI, ci = i - o * CI;
        wl[i] = w[(size_t)(o0 + o) * CI + ci];
    }
    if (t < 6) {
        float s = g[o0 + t] * rsqrtf(1.0f + 1e-5f);
        sb[t] = s; bb[t] = bias[o0 + t] * s + be[o0 + t];
    }
    __syncthreads();
    int gn = pc * 256 + t;
    int b = gn >> 12;
    const float* ip = in + (size_t)b * CI * NPOS + (gn & 4095);
    float acc[6];
#pragma unroll
    for (int o = 0; o < 6; o++) acc[o] = 0.f;
#pragma unroll
    for (int ci = 0; ci < CI; ci++) {
        float v = ip[(size_t)ci * NPOS];
#pragma unroll
        for (int o = 0; o < 6; o++) acc[o] += v * wl[o * CI + ci];
    }
    float* op = out + (size_t)gn * 48 + o0;
#pragma unroll
    for (int o = 0; o < 6; o++) {
        float z = acc[o] * sb[o] + bb[o];
        op[o] = z > 0.f ? z : 0.f;
    }
}

// Q,K,V co-split x8.  grid = 3 grp * 32 pc * 8 cc = 768 blocks.
__global__ void qkv_kernel(const float* __restrict__ Y1, const float* __restrict__ S1,
                           const float* __restrict__ Wq, const float* __restrict__ Wk,
                           const float* __restrict__ Wv, ushort_t* __restrict__ Qb,
                           ushort_t* __restrict__ Kb, ushort_t* __restrict__ Vt) {
    int grp = blockIdx.x >> 8;
    int r = blockIdx.x & 255;
    int pc = r >> 3, cc = r & 7;
    int o0 = cc * 6;
    const float* in = (grp == 2) ? S1 : Y1;
    const float* w = (grp == 0) ? Wq : (grp == 1) ? Wk : Wv;
    __shared__ float wl[48 * 6];   // [d][o] for the 6 outputs
    int t = threadIdx.x;
    for (int i = t; i < 48 * 6; i += 256) {
        int d = i / 6, o = i - d * 6;
        wl[i] = w[(size_t)d * 48 + o0 + o];
    }
    __syncthreads();
    int gn = pc * 256 + t;
    const float* ip = in + (size_t)gn * 48;
    float acc[6];
#pragma unroll
    for (int o = 0; o < 6; o++) acc[o] = 0.f;
#pragma unroll
    for (int d = 0; d < 48; d++) {
        float v = ip[d];
#pragma unroll
        for (int o = 0; o < 6; o++) acc[o] += v * wl[d * 6 + o];
    }
    if (grp < 2) {
        ushort_t* op = (grp == 0 ? Qb : Kb) + (size_t)gn * 48 + o0;
#pragma unroll
        for (int o = 0; o < 6; o++) op[o] = f2bf(acc[o]);
    } else {
        int b = gn >> 12; int n = gn & 4095;
#pragma unroll
        for (int o = 0; o < 6; o++)
            Vt[((size_t)(b * 48 + o0 + o) << 12) + n] = f2bf(acc[o]);
    }
}

// Pass 1: column (over-q) softmax stats via swapped MFMA S^T = K*Q^T.
__global__ void attn_stats_mfma_kernel(const ushort_t* __restrict__ Qb,
                                       const ushort_t* __restrict__ Kb,
                                       float* __restrict__ pm, float* __restrict__ ps) {
    int bid = blockIdx.x;
    int qs = bid & (QS - 1); int kb = (bid >> 3) & 63; int b = bid >> 9;
    int t = threadIdx.x; int wv = t >> 6; int lane = t & 63;
    int lr = lane & 15, g = lane >> 4;
    const float scale = 0.14433756729740643f;
    int key = kb * 64 + wv * 16 + lr;
    const ushort_t* krow = Kb + ((size_t)(b * NPOS + key)) * 48;
    v4s ka[3];
#pragma unroll
    for (int db = 0; db < 3; db++) ka[db] = *(const v4s*)(krow + 16 * db + 4 * g);
    float m[4], s[4];
#pragma unroll
    for (int r = 0; r < 4; r++) { m[r] = -1e30f; s[r] = 0.f; }
    for (int qt = 0; qt < 512 / 16; qt++) {
        int q = qs * 512 + qt * 16 + lr;
        const ushort_t* qrow = Qb + ((size_t)(b * NPOS + q)) * 48;
        v4f acc = {0.f, 0.f, 0.f, 0.f};
#pragma unroll
        for (int db = 0; db < 3; db++)
            acc = __builtin_amdgcn_mfma_f32_16x16x16bf16_1k(
                ka[db], *(const v4s*)(qrow + 16 * db + 4 * g), acc, 0, 0, 0);
#pragma unroll
        for (int r = 0; r < 4; r++) {
            float sc = acc[r] * scale;
            float mn = fmaxf(m[r], sc);
            s[r] = s[r] * __expf(m[r] - mn) + __expf(sc - mn);
            m[r] = mn;
        }
    }
#pragma unroll
    for (int off = 1; off < 16; off <<= 1) {
#pragma unroll
        for (int r = 0; r < 4; r++) {
            float mo = __shfl_xor(m[r], off);
            float so = __shfl_xor(s[r], off);
            float mn = fmaxf(m[r], mo);
            s[r] = s[r] * __expf(m[r] - mn) + so * __expf(mo - mn);
            m[r] = mn;
        }
    }
    if (lr == 0) {
        int idx = (b * QS + qs) * NPOS + kb * 64 + wv * 16 + 4 * g;
        v4f mm = {m[0], m[1], m[2], m[3]};
        v4f ss = {s[0], s[1], s[2], s[3]};
        *(v4f*)&pm[idx] = mm;
        *(v4f*)&ps[idx] = ss;
    }
}

__global__ void stats_reduce_kernel(const float* __restrict__ pm, const float* __restrict__ ps,
                                    float* __restrict__ colm, float* __restrict__ colinv) {
    int idx = blockIdx.x * 128 + threadIdx.x;
    if (idx >= BB * NPOS) return;
    int b = idx >> 12; int k = idx & 4095;
    float m = -1e30f;
#pragma unroll
    for (int qs = 0; qs < QS; qs++) m = fmaxf(m, pm[(size_t)(b * QS + qs) * NPOS + k]);
    float s = 0.f;
#pragma unroll
    for (int qs = 0; qs < QS; qs++)
        s += ps[(size_t)(b * QS + qs) * NPOS + k] * __expf(pm[(size_t)(b * QS + qs) * NPOS + k] - m);
    colm[idx] = m;
    colinv[idx] = 1.0f / s;
}

// Pass 2: x = A*V via MFMA, swapped-MFMA chaining.  xpart layout (b,ks,q,48).
__global__ void attn_pv_mfma_kernel(const ushort_t* __restrict__ Qb,
                                    const ushort_t* __restrict__ Kb,
                                    const ushort_t* __restrict__ Vt,
                                    const float* __restrict__ colm,
                                    const float* __restrict__ colinv,
                                    float* __restrict__ xpart) {
    int bid = blockIdx.x;
    int ks = bid & (KS - 1); int qb = (bid >> 2) & 63; int b = bid >> 8;
    int t = threadIdx.x; int wv = t >> 6; int lane = t & 63;
    int lr = lane & 15, g = lane >> 4;
    const float scale = 0.14433756729740643f;
    int q0 = qb * 64 + wv * 16;
    const ushort_t* qrow = Qb + ((size_t)(b * NPOS + q0 + lr)) * 48;
    v4s qf[3];
#pragma unroll
    for (int db = 0; db < 3; db++) qf[db] = *(const v4s*)(qrow + 16 * db + 4 * g);
    v4f xacc[3];
#pragma unroll
    for (int nt = 0; nt < 3; nt++) xacc[nt] = (v4f){0.f, 0.f, 0.f, 0.f};
    for (int kt = 0; kt < 4096 / KS / 64; kt++) {
        int kb0 = ks * (4096 / KS) + kt * 64;
        v4s p[4];
#pragma unroll
        for (int tm = 0; tm < 4; tm++) {
            const ushort_t* krow = Kb + ((size_t)(b * NPOS + kb0 + 16 * tm + lr)) * 48;
            v4f acc = {0.f, 0.f, 0.f, 0.f};
#pragma unroll
            for (int db = 0; db < 3; db++)
                acc = __builtin_amdgcn_mfma_f32_16x16x16bf16_1k(
                    *(const v4s*)(krow + 16 * db + 4 * g), qf[db], acc, 0, 0, 0);
            int kc = b * NPOS + kb0 + 16 * tm + 4 * g;
            v4f cm = *(const v4f*)&colm[kc];
            v4f ci = *(const v4f*)&colinv[kc];
            v4s pp;
#pragma unroll
            for (int r = 0; r < 4; r++)
                pp[r] = (short)f2bf(__expf(acc[r] * scale - cm[r]) * ci[r]);
            p[tm] = pp;
        }
#pragma unroll
        for (int nt = 0; nt < 3; nt++) {
            const ushort_t* vrow = Vt + ((size_t)(b * 48 + 16 * nt + lr) << 12) + kb0;
#pragma unroll
            for (int tm = 0; tm < 4; tm++)
                xacc[nt] = __builtin_amdgcn_mfma_f32_16x16x16bf16_1k(
                    p[tm], *(const v4s*)(vrow + 16 * tm + 4 * g), xacc[nt], 0, 0, 0);
        }
    }
    // lane: d = 16nt+lr, q = q0+4g+r -> xpart[((b*KS+ks)*4096 + q)*48 + d]
#pragma unroll
    for (int nt = 0; nt < 3; nt++)
#pragma unroll
        for (int r = 0; r < 4; r++)
            xpart[(((size_t)(b * KS + ks) << 12) + q0 + 4 * g + r) * 48 + 16 * nt + lr] = xacc[nt][r];
}

// Reduce x partials + conv1x1(w_o) + BN + ReLU, * S_pe -> out ch [0,48).  co-split x8.
__global__ void z_out_kernel(const float* __restrict__ xpart, const float* __restrict__ w_o,
                             const float* __restrict__ b_o, const float* __restrict__ g_o,
                             const float* __restrict__ be_o, const float* __restrict__ S_pe,
                             float* __restrict__ out) {
    int pc = blockIdx.x >> 3, cc = blockIdx.x & 7;
    int o0 = cc * 6;
    __shared__ float wl[6 * 48];
    __shared__ float sb[6], bb[6];
    int t = threadIdx.x;
    for (int i = t; i < 6 * 48; i += 256) {
        int o = i / 48, d = i - o * 48;
        wl[i] = w_o[(size_t)(o0 + o) * 48 + d];
    }
    if (t < 6) {
        float s = g_o[o0 + t] * rsqrtf(1.f + 1e-5f);
        sb[t] = s; bb[t] = b_o[o0 + t] * s + be_o[o0 + t];
    }
    __syncthreads();
    int gn = pc * 256 + t;
    int b = gn >> 12; int n = gn & 4095;
    float x[48];
#pragma unroll
    for (int d = 0; d < 48; d++) x[d] = 0.f;
#pragma unroll
    for (int ks = 0; ks < KS; ks++) {
        const v4f* p = (const v4f*)(xpart + (((size_t)(b * KS + ks) << 12) + n) * 48);
#pragma unroll
        for (int d4 = 0; d4 < 12; d4++) {
            v4f v = p[d4];
#pragma unroll
            for (int j = 0; j < 4; j++) x[d4 * 4 + j] += v[j];
        }
    }
#pragma unroll
    for (int o = 0; o < 6; o++) {
        float acc = 0.f;
#pragma unroll
        for (int d = 0; d < 48; d++) acc += wl[o * 48 + d] * x[d];
        float z = acc * sb[o] + bb[o];
        z = z > 0.f ? z : 0.f;
        out[((size_t)b * 96 + o0 + o) * NPOS + n] = z * S_pe[((size_t)b * 48 + o0 + o) * NPOS + n];
    }
}

// ---- conv3d via implicit-GEMM MFMA ----

// Y_pe (B,96,4096) fp32 -> Y_pad (B,18,18,18,96) bf16, halo zeroed inline
__global__ void pad_build_kernel(const float* __restrict__ Y_pe, ushort_t* __restrict__ Ypad) {
    int idx = blockIdx.x * 256 + threadIdx.x;   // over B*5832 cells * 24 ci4
    if (idx >= BB * 5832 * 24) return;
    int ci4 = idx % 24;
    int cell = idx / 24;
    int wp = cell % 18; int c2 = cell / 18;
    int hp = c2 % 18; int c3 = c2 / 18;
    int zp = c3 % 18; int b = c3 / 18;
    ushort_t pk[4] = {0, 0, 0, 0};
    if (zp >= 1 && zp <= 16 && hp >= 1 && hp <= 16 && wp >= 1 && wp <= 16) {
        int n = (zp - 1) * 256 + (hp - 1) * 16 + (wp - 1);
#pragma unroll
        for (int j = 0; j < 4; j++)
            pk[j] = f2bf(Y_pe[((size_t)(b * 96 + ci4 * 4 + j) << 12) + n]);
    }
    *(v4s*)&Ypad[(size_t)idx * 4] = *(v4s*)pk;
}

// w3 (96co, 96ci, 27tap) fp32 -> wr [27][96co][96ci] bf16
__global__ void w3_repack_kernel(const float* __restrict__ w3, ushort_t* __restrict__ wr) {
    int idx = blockIdx.x * 256 + threadIdx.x;
    if (idx >= 27 * 96 * 96) return;
    int ci = idx % 96;
    int t2 = idx / 96;
    int co = t2 % 96;
    int tap = t2 / 96;
    wr[idx] = f2bf(w3[(size_t)(co * 96 + ci) * 27 + tap]);
}

// implicit-GEMM conv.  Y3 out layout: position-major (B,4096,96) fp32.
__global__ void conv3d_mfma_kernel(const ushort_t* __restrict__ Ypad,
                                   const ushort_t* __restrict__ wr,
                                   const float* __restrict__ b3,
                                   float* __restrict__ Y3) {
    int bid = blockIdx.x;
    int b = bid / 384;
    int r = bid % 384;
    int cot = r % 6;
    int zhq = r / 6;                 // 0..63
    int t = threadIdx.x; int wv = t >> 6; int lane = t & 63;
    int z = zhq >> 2;
    int h = (zhq & 3) * 4 + wv;
    int lr = lane & 15, g4 = (lane >> 4) * 4;
    float bv = b3[cot * 16 + lr];
    v4f acc = {bv, bv, bv, bv};
    for (int kd = 0; kd < 3; kd++) {
        for (int kh = 0; kh < 3; kh++) {
            const ushort_t* arow = Ypad + (((size_t)(b * 18 + z + kd) * 18 + h + kh) * 18 + lr) * 96 + g4;
            int tap0 = (kd * 3 + kh) * 3;
#pragma unroll
            for (int kw = 0; kw < 3; kw++) {
                const ushort_t* abase = arow + (size_t)kw * 96;
                const ushort_t* bbase = wr + ((size_t)((tap0 + kw) * 96 + cot * 16 + lr)) * 96 + g4;
#pragma unroll
                for (int cich = 0; cich < 6; cich++)
                    acc = __builtin_amdgcn_mfma_f32_16x16x16bf16_1k(
                        *(const v4s*)(abase + cich * 16),
                        *(const v4s*)(bbase + cich * 16), acc, 0, 0, 0);
            }
        }
    }
    // D: col(lr)=co, rows(4g+r)=w -> Y3[(b,pos,co)]
    int pos = z * 256 + h * 16 + g4;
#pragma unroll
    for (int r2 = 0; r2 < 4; r2++)
        Y3[(((size_t)b << 12) + pos + r2) * 96 + cot * 16 + lr] = acc[r2];
}

// conv1x1(w_y2) + BN + ReLU on Y3 (B,4096,96) -> out ch [48,96).  co-split x8.
__global__ void y2_out_kernel(const float* __restrict__ Y3, const float* __restrict__ w_y2,
                              const float* __restrict__ b_y2, const float* __restrict__ g_y2,
                              const float* __restrict__ be_y2, float* __restrict__ out) {
    int pc = blockIdx.x >> 3, cc = blockIdx.x & 7;
    int o0 = cc * 6;
    __shared__ float wl[6 * 96];
    __shared__ float sb[6], bb[6];
    int t = threadIdx.x;
    for (int i = t; i < 6 * 96; i += 256) {
        int o = i / 96, ci = i - o * 96;
        wl[i] = w_y2[(size_t)(o0 + o) * 96 + ci];
    }
    if (t < 6) {
        float s = g_y2[o0 + t] * rsqrtf(1.f + 1e-5f);
        sb[t] = s; bb[t] = b_y2[o0 + t] * s + be_y2[o0 + t];
    }
    __syncthreads();
    int gn = pc * 256 + t;
    int b = gn >> 12; int n = gn & 4095;
    const v4f* ip = (const v4f*)(Y3 + (size_t)gn * 96);
    float acc[6];
#pragma unroll
    for (int o = 0; o < 6; o++) acc[o] = 0.f;
#pragma unroll
    for (int c4 = 0; c4 < 24; c4++) {
        v4f v = ip[c4];
#pragma unroll
        for (int j = 0; j < 4; j++)
#pragma unroll
            for (int o = 0; o < 6; o++) acc[o] += v[j] * wl[o * 96 + c4 * 4 + j];
    }
#pragma unroll
    for (int o = 0; o < 6; o++) {
        float z = acc[o] * sb[o] + bb[o];
        out[((size_t)b * 96 + 48 + o0 + o) * NPOS + n] = z > 0.f ? z : 0.f;
    }
}

extern "C" void kernel_launch(void* const* d_in, const int* in_sizes, int n_in,
                              void* d_out, int out_size, void* d_ws, size_t ws_size,
                              hipStream_t stream) {
    const float* Y    = (const float*)d_in[0];
    const float* S    = (const float*)d_in[1];
    const float* w_s  = (const float*)d_in[2];
    const float* b_s  = (const float*)d_in[3];
    const float* g_s  = (const float*)d_in[4];
    const float* be_s = (const float*)d_in[5];
    const float* w_y  = (const float*)d_in[6];
    const float* b_y  = (const float*)d_in[7];
    const float* g_y  = (const float*)d_in[8];
    const float* be_y = (const float*)d_in[9];
    const float* Wq   = (const float*)d_in[10];
    const float* Wk   = (const float*)d_in[11];
    const float* Wv   = (const float*)d_in[12];
    const float* w_o  = (const float*)d_in[13];
    const float* b_o  = (const float*)d_in[14];
    const float* g_o  = (const float*)d_in[15];
    const float* be_o = (const float*)d_in[16];
    const float* w3   = (const float*)d_in[17];
    const float* b3   = (const float*)d_in[18];
    const float* w_y2 = (const float*)d_in[19];
    const float* b_y2 = (const float*)d_in[20];
    const float* g_y2 = (const float*)d_in[21];
    const float* be_y2= (const float*)d_in[22];
    float* out = (float*)d_out;

    float* ws = (float*)d_ws;
    float* S_pe   = ws;                        // 393216
    float* Y_pe   = ws + 393216;               // 786432
    float* S1     = ws + 1179648;              // 393216
    float* Y1     = ws + 1572864;              // 393216
    ushort_t* Qb  = (ushort_t*)(ws + 1966080); // 196608 f
    ushort_t* Kb  = (ushort_t*)(ws + 2162688); // 196608 f
    ushort_t* Vt  = (ushort_t*)(ws + 2359296); // 196608 f
    float* pm     = ws + 2555904;              // 65536
    float* ps     = ws + 2621440;              // 65536
    float* colm   = ws + 2686976;              // 8192
    float* colinv = ws + 2695168;              // 8192
    float* xpart  = ws + 2703360;              // (b,ks,q,48) 1572864
    float* Y3     = ws + 4276224;              // (b,n,96) 786432
    ushort_t* Ypad= (ushort_t*)(ws + 5062656); // 559872 f
    ushort_t* wr  = (ushort_t*)(ws + 5622528); // 124416 f

    // conv3d weight repack (independent)
    w3_repack_kernel<<<972, 256, 0, stream>>>(w3, wr);
    // 1. positional encodings
    pe_add_kernel<<<1536, 256, 0, stream>>>(S, S_pe, 48, 16);
    pe_add_kernel<<<3072, 256, 0, stream>>>(Y, Y_pe, 96, 32);
    // conv3d input pad (bf16, halo zeroed inline)
    pad_build_kernel<<<1094, 256, 0, stream>>>(Y_pe, Ypad);
    // 2. projections (conv1x1 + BN + ReLU) -> (B,N,48), co-split x8
    proj_kernel<48><<<256, 256, 0, stream>>>(S_pe, w_s, b_s, g_s, be_s, S1);
    proj_kernel<96><<<256, 256, 0, stream>>>(Y_pe, w_y, b_y, g_y, be_y, Y1);
    // 3. Q, K row-major bf16; V transposed bf16, co-split x8
    qkv_kernel<<<768, 256, 0, stream>>>(Y1, S1, Wq, Wk, Wv, Qb, Kb, Vt);
    // 4. column-softmax stats (softmax over q, per key k), MFMA
    attn_stats_mfma_kernel<<<BB * 64 * QS, 256, 0, stream>>>(Qb, Kb, pm, ps);
    stats_reduce_kernel<<<64, 128, 0, stream>>>(pm, ps, colm, colinv);
    // 5. x = A @ V partials, MFMA
    attn_pv_mfma_kernel<<<BB * 64 * KS, 256, 0, stream>>>(Qb, Kb, Vt, colm, colinv, xpart);
    // 6. 3x3x3 conv branch, implicit-GEMM MFMA
    conv3d_mfma_kernel<<<768, 256, 0, stream>>>(Ypad, wr, b3, Y3);
    // 7. outputs, co-split x8
    z_out_kernel<<<256, 256, 0, stream>>>(xpart, w_o, b_o, g_o, be_o, S_pe, out);
    y2_out_kernel<<<256, 256, 0, stream>>>(Y3, w_y2, b_y2, g_y2, be_y2, out);
}